// Round 5
// baseline (2289.552 us; speedup 1.0000x reference)
//
#include <hip/hip_runtime.h>
#include <stdint.h>

// RNNModel: h_{t+1} = hardtanh(x_t @ W_in^T + h_t @ W_h^T), out = h_T @ W_out^T
// B=1024 T=2048 D=13 H=128 O=2, fp32 in/out.
//
// Round 5: MFMA 16x16x32 bf16 hi/lo (3-term) — overhead reduction.
//  - 64 blocks (16-batch groups) x 8 waves, ONE m-tile per wave (2 waves/SIMD
//    for latency hiding; MFMA pipe per CU-step = 8mt*15mfma*19.4cy/4SIMD ~ 582cy).
//  - h in LDS stored PRE-PERMUTED in B-fragment order:
//      pos = kt*32 + g*8 + half*4 + j  <->  k = 32*kt + 16*half + 4*g + j
//    so each wave reads one ds_read_b128 per (kt, hi/lo) — conflict-free
//    (row stride 136 shorts = 17 quads, odd -> quad index (n+g)%8 balanced).
//    D-layout epilogue writes 4 consecutive r -> contiguous b64, still.
//  - x prefetched 2 steps ahead (two named reg buffers, loop unrolled x2)
//    to cover cold-HBM latency (~900cy).
//  - One __syncthreads per step (double-buffered h).

#define RNN_B 1024
#define RNN_T 2048
#define RNN_D 13
#define RNN_H 128
#define RNN_O 2

#define NB 16                 // batches per block (MFMA n-dim)
#define NWAVE 8
#define NTHR (NWAVE * 64)
#define NKT 5                 // 4 h k-tiles + 1 x k-tile
#define ROWS 136              // shorts per batch row: 4*32 data + 8 pad (17 quads, odd)

using f32x4 = __attribute__((ext_vector_type(4))) float;
using v8s   = __attribute__((ext_vector_type(8))) short;

__device__ __forceinline__ short f2bf(float f) {
    union { float f; uint32_t u; } c; c.f = f;
    uint32_t u = c.u + 0x7fffu + ((c.u >> 16) & 1u);   // RNE
    return (short)(u >> 16);
}
__device__ __forceinline__ float bf2f(short s) {
    union { uint32_t u; float f; } c; c.u = ((uint32_t)(uint16_t)s) << 16;
    return c.f;
}

__device__ __forceinline__ void rnn_step(
    int cur, int nxt, float* xc, int tnext,
    const float* __restrict__ xrow,
    const v8s* whi, const v8s* wlo,
    short (*Hhi)[NB][ROWS], short (*Hlo)[NB][ROWS],
    int n, int g, int wid)
{
    // x B-fragment for this step (upper k-half zero)
    v8s xh, xl;
    #pragma unroll
    for (int j = 0; j < 4; ++j) {
        const int d = 4 * g + j;
        const float v = (d < RNN_D) ? xc[j] : 0.0f;
        const short h1 = f2bf(v);
        xh[j] = h1;                 xh[4 + j] = 0;
        xl[j] = f2bf(v - bf2f(h1)); xl[4 + j] = 0;
    }
    // prefetch x two steps ahead (vmcnt waited only at its use, 2 iters later)
    if (tnext < RNN_T) {
        const float* xp = xrow + (size_t)tnext * RNN_D;
        #pragma unroll
        for (int j = 0; j < 4; ++j) { const int d = 4 * g + j; xc[j] = xp[d > 12 ? 12 : d]; }
    }

    // B-fragments of h: one b128 per (kt, hi/lo), conflict-free permuted layout
    v8s bh[4], bl[4];
    #pragma unroll
    for (int kt = 0; kt < 4; ++kt) {
        bh[kt] = *(const v8s*)&Hhi[cur][n][kt * 32 + g * 8];
        bl[kt] = *(const v8s*)&Hlo[cur][n][kt * 32 + g * 8];
    }

    f32x4 a1 = {0.f, 0.f, 0.f, 0.f};
    f32x4 a2 = {0.f, 0.f, 0.f, 0.f};
    f32x4 a3 = {0.f, 0.f, 0.f, 0.f};
    #pragma unroll
    for (int kt = 0; kt < 4; ++kt) {
        a1 = __builtin_amdgcn_mfma_f32_16x16x32_bf16(whi[kt], bh[kt], a1, 0, 0, 0);
        a2 = __builtin_amdgcn_mfma_f32_16x16x32_bf16(whi[kt], bl[kt], a2, 0, 0, 0);
        a3 = __builtin_amdgcn_mfma_f32_16x16x32_bf16(wlo[kt], bh[kt], a3, 0, 0, 0);
    }
    a1 = __builtin_amdgcn_mfma_f32_16x16x32_bf16(whi[4], xh, a1, 0, 0, 0);
    a2 = __builtin_amdgcn_mfma_f32_16x16x32_bf16(whi[4], xl, a2, 0, 0, 0);
    a3 = __builtin_amdgcn_mfma_f32_16x16x32_bf16(wlo[4], xh, a3, 0, 0, 0);

    // epilogue: rows 16*wid + 4g + r, col n -> permuted pos, contiguous b64
    short hs[4], ls[4];
    #pragma unroll
    for (int r = 0; r < 4; ++r) {
        float v = a1[r] + a2[r] + a3[r];
        v = fminf(fmaxf(v, -1.0f), 1.0f);
        const short hh = f2bf(v);
        hs[r] = hh;
        ls[r] = f2bf(v - bf2f(hh));
    }
    int2 ph, pl;
    ph.x = (int)(((uint32_t)(uint16_t)hs[1] << 16) | (uint16_t)hs[0]);
    ph.y = (int)(((uint32_t)(uint16_t)hs[3] << 16) | (uint16_t)hs[2]);
    pl.x = (int)(((uint32_t)(uint16_t)ls[1] << 16) | (uint16_t)ls[0]);
    pl.y = (int)(((uint32_t)(uint16_t)ls[3] << 16) | (uint16_t)ls[2]);
    const int wp = (wid >> 1) * 32 + g * 8 + (wid & 1) * 4;
    *(int2*)&Hhi[nxt][n][wp] = ph;
    *(int2*)&Hlo[nxt][n][wp] = pl;
    __syncthreads();
}

__global__ __launch_bounds__(NTHR, 2) void rnn_mfma8_kernel(
    const float* __restrict__ xs,     // [B, T, D]
    const float* __restrict__ W_in,   // [H, D]
    const float* __restrict__ W_h,    // [H, H]
    const float* __restrict__ W_out,  // [O, H]
    float* __restrict__ out)          // [B, O]
{
    __shared__ short Hhi[2][NB][ROWS];
    __shared__ short Hlo[2][NB][ROWS];

    const int tid  = threadIdx.x;
    const int lane = tid & 63;
    const int wid  = tid >> 6;       // wave 0..7 = m-tile index
    const int n    = lane & 15;      // batch col / A-row within tile
    const int g    = lane >> 4;      // k-group 0..3
    const int b0   = blockIdx.x * NB;

    // ---- A fragments: W rows 16*wid + n, bf16 hi/lo, 5 k-tiles ----
    v8s whi[NKT], wlo[NKT];
    {
        const int row = 16 * wid + n;
        #pragma unroll
        for (int kt = 0; kt < NKT; ++kt) {
            v8s h8, l8;
            #pragma unroll
            for (int j = 0; j < 4; ++j) {
                float w1, w2;
                if (kt < 4) {
                    w1 = W_h[row * RNN_H + 32 * kt + 4 * g + j];
                    w2 = W_h[row * RNN_H + 32 * kt + 16 + 4 * g + j];
                } else {
                    const int kx = 4 * g + j;
                    w1 = (kx < RNN_D) ? W_in[row * RNN_D + kx] : 0.0f;
                    w2 = 0.0f;
                }
                const short h1 = f2bf(w1);
                const short h2 = f2bf(w2);
                h8[j] = h1; h8[4 + j] = h2;
                l8[j] = f2bf(w1 - bf2f(h1));
                l8[4 + j] = f2bf(w2 - bf2f(h2));
            }
            whi[kt] = h8;
            wlo[kt] = l8;
        }
    }

    // ---- zero-init buffer 0 (h0 = 0) ----
    for (int idx = tid; idx < NB * ROWS; idx += NTHR) {
        (&Hhi[0][0][0])[idx] = 0;
        (&Hlo[0][0][0])[idx] = 0;
    }

    // ---- x prefetch, depth 2 ----
    const float* xrow = xs + (size_t)(b0 + n) * RNN_T * RNN_D;
    float xa[4], xb[4];
    #pragma unroll
    for (int j = 0; j < 4; ++j) {
        const int d = 4 * g + j;
        xa[j] = xrow[d > 12 ? 12 : d];
        xb[j] = xrow[RNN_D + (d > 12 ? 12 : d)];
    }
    __syncthreads();

    // ---- recurrence, unrolled x2 (static buffers, static prefetch slots) ----
    for (int t = 0; t < RNN_T; t += 2) {
        rnn_step(0, 1, xa, t + 2, xrow, whi, wlo, Hhi, Hlo, n, g, wid);
        rnn_step(1, 0, xb, t + 3, xrow, whi, wlo, Hhi, Hlo, n, g, wid);
    }

    // ---- epilogue: out[b][o] = sum_i W_out[o][i] * h_T[i] (final h in buf 0) ----
    if (wid == 0 && lane < NB * RNN_O) {
        const int nn = lane & 15;
        const int o  = lane >> 4;
        float acc = 0.0f;
        for (int i = 0; i < RNN_H; ++i) {
            const int kt = i >> 5, rem = i & 31, half = rem >> 4, r4 = rem & 15;
            const int pos = kt * 32 + (r4 >> 2) * 8 + half * 4 + (r4 & 3);
            const float hv = bf2f(Hhi[0][nn][pos]) + bf2f(Hlo[0][nn][pos]);
            acc = fmaf(W_out[o * RNN_H + i], hv, acc);
        }
        out[(size_t)(b0 + nn) * RNN_O + o] = acc;
    }
}

extern "C" void kernel_launch(void* const* d_in, const int* in_sizes, int n_in,
                              void* d_out, int out_size, void* d_ws, size_t ws_size,
                              hipStream_t stream) {
    const float* xs    = (const float*)d_in[0];
    const float* W_in  = (const float*)d_in[1];
    const float* W_h   = (const float*)d_in[2];
    const float* W_out = (const float*)d_in[3];
    float* out = (float*)d_out;

    rnn_mfma8_kernel<<<RNN_B / NB, NTHR, 0, stream>>>(xs, W_in, W_h, W_out, out);
}

// Round 6
// 1241.730 us; speedup vs baseline: 1.8438x; 1.8438x over previous
//
#include <hip/hip_runtime.h>
#include <stdint.h>

// RNNModel: h_{t+1} = hardtanh(x_t @ W_in^T + h_t @ W_h^T), out = h_T @ W_out^T
// B=1024 T=2048 D=13 H=128 O=2, fp32 in/out.
//
// Round 6: round-4 skeleton (4 waves x 2 m-tiles, 1 wave/SIMD, NB=16, 64 blocks)
// with the VALU epilogue cut down:
//  - v_cvt_pk_bf16_f32 (HW packed cvt) replaces manual 5-op RNE f2bf for all
//    in-loop conversions (residual lo-split is rounding-mode-safe).
//  - fmed3 clamp; epilogue writes the cvt_pk-packed dwords directly.
//  - h in LDS in FRAGMENT-ORDERED layout: pos = 32*(tile>>1)+8*g+4*(tile&1)+j
//    for k = 16*tile+4*g+j -> one ds_read_b128 per (kt, hi/lo), b64 writes.
//  - x prefetched depth-2 into NAMED scalars via x2-unrolled macro (round 5's
//    regression was address-taken local arrays -> scratch; avoided here).
//  - One __syncthreads per step, double-buffered h.

#define RNN_B 1024
#define RNN_T 2048
#define RNN_D 13
#define RNN_H 128
#define RNN_O 2

#define NB 16
#define NWAVE 4
#define NTHR (NWAVE * 64)
#define ROWS 136              // shorts per batch row: 128 data + 8 pad (17 quads)

using f32x4 = __attribute__((ext_vector_type(4))) float;
using v8s   = __attribute__((ext_vector_type(8))) short;

__device__ __forceinline__ short f2bf(float f) {           // setup only
    union { float f; uint32_t u; } c; c.f = f;
    uint32_t u = c.u + 0x7fffu + ((c.u >> 16) & 1u);
    return (short)(u >> 16);
}
__device__ __forceinline__ float bf2fs(short s) {
    union { uint32_t u; float f; } c; c.u = ((uint32_t)(uint16_t)s) << 16;
    return c.f;
}
__device__ __forceinline__ float bitf(uint32_t u) {
    union { uint32_t u; float f; } c; c.u = u; return c.f;
}
__device__ __forceinline__ uint32_t cvtpk(float a, float b) {  // [bf16(b)|bf16(a)]
    uint32_t r;
    asm("v_cvt_pk_bf16_f32 %0, %1, %2" : "=v"(r) : "v"(a), "v"(b));
    return r;
}
__device__ __forceinline__ v8s pack4(uint32_t a, uint32_t b, uint32_t c, uint32_t d) {
    union { uint32_t u[4]; v8s s; } z;
    z.u[0] = a; z.u[1] = b; z.u[2] = c; z.u[3] = d; return z.s;
}
__device__ __forceinline__ float clamp1(float v) {
    return __builtin_amdgcn_fmed3f(v, -1.0f, 1.0f);
}

// one recurrence step; X0..X3 are named lvalue scalars (current x), refilled
// with x[TPF] (depth-2 prefetch). CUR/NXT are literal buffer indices.
#define STEP(CUR, NXT, X0, X1, X2, X3, TPF)                                      \
  do {                                                                           \
    v8s bh[4], bl[4];                                                            \
    bh[0] = *(const v8s*)&Hhi[CUR][n][g8];                                       \
    bh[1] = *(const v8s*)&Hhi[CUR][n][32 + g8];                                  \
    bh[2] = *(const v8s*)&Hhi[CUR][n][64 + g8];                                  \
    bh[3] = *(const v8s*)&Hhi[CUR][n][96 + g8];                                  \
    bl[0] = *(const v8s*)&Hlo[CUR][n][g8];                                       \
    bl[1] = *(const v8s*)&Hlo[CUR][n][32 + g8];                                  \
    bl[2] = *(const v8s*)&Hlo[CUR][n][64 + g8];                                  \
    bl[3] = *(const v8s*)&Hlo[CUR][n][96 + g8];                                  \
    float m0 = X0, m1 = X1, m2 = X2, m3 = X3;                                    \
    if (g == 3) { m1 = 0.0f; m2 = 0.0f; m3 = 0.0f; }                             \
    uint32_t xh01 = cvtpk(m0, m1), xh23 = cvtpk(m2, m3);                         \
    float q0 = m0 - bitf(xh01 << 16);                                            \
    float q1 = m1 - bitf(xh01 & 0xffff0000u);                                    \
    float q2 = m2 - bitf(xh23 << 16);                                            \
    float q3 = m3 - bitf(xh23 & 0xffff0000u);                                    \
    uint32_t xl01 = cvtpk(q0, q1), xl23 = cvtpk(q2, q3);                         \
    v8s xh = pack4(xh01, xh23, 0u, 0u);                                          \
    v8s xl = pack4(xl01, xl23, 0u, 0u);                                          \
    if ((TPF) < RNN_T) {                                                         \
      const float* xp = xrow + (size_t)(TPF) * RNN_D;                            \
      X0 = xp[d0]; X1 = xp[d1]; X2 = xp[d2]; X3 = xp[d3];                        \
    }                                                                            \
    f32x4 A1 = {0.f,0.f,0.f,0.f};                                                \
    f32x4 A2 = A1, A3 = A1, B1 = A1, B2 = A1, B3 = A1;                           \
    _Pragma("unroll")                                                            \
    for (int kt = 0; kt < 4; ++kt) {                                             \
      A1 = __builtin_amdgcn_mfma_f32_16x16x32_bf16(whiA[kt], bh[kt], A1, 0,0,0); \
      B1 = __builtin_amdgcn_mfma_f32_16x16x32_bf16(whiB[kt], bh[kt], B1, 0,0,0); \
      A2 = __builtin_amdgcn_mfma_f32_16x16x32_bf16(whiA[kt], bl[kt], A2, 0,0,0); \
      B2 = __builtin_amdgcn_mfma_f32_16x16x32_bf16(whiB[kt], bl[kt], B2, 0,0,0); \
      A3 = __builtin_amdgcn_mfma_f32_16x16x32_bf16(wloA[kt], bh[kt], A3, 0,0,0); \
      B3 = __builtin_amdgcn_mfma_f32_16x16x32_bf16(wloB[kt], bh[kt], B3, 0,0,0); \
    }                                                                            \
    A1 = __builtin_amdgcn_mfma_f32_16x16x32_bf16(whiA[4], xh, A1, 0,0,0);        \
    B1 = __builtin_amdgcn_mfma_f32_16x16x32_bf16(whiB[4], xh, B1, 0,0,0);        \
    A2 = __builtin_amdgcn_mfma_f32_16x16x32_bf16(whiA[4], xl, A2, 0,0,0);        \
    B2 = __builtin_amdgcn_mfma_f32_16x16x32_bf16(whiB[4], xl, B2, 0,0,0);        \
    A3 = __builtin_amdgcn_mfma_f32_16x16x32_bf16(wloA[4], xh, A3, 0,0,0);        \
    B3 = __builtin_amdgcn_mfma_f32_16x16x32_bf16(wloB[4], xh, B3, 0,0,0);        \
    {                                                                            \
      float v0 = clamp1(A1[0] + A2[0] + A3[0]);                                  \
      float v1 = clamp1(A1[1] + A2[1] + A3[1]);                                  \
      float v2 = clamp1(A1[2] + A2[2] + A3[2]);                                  \
      float v3 = clamp1(A1[3] + A2[3] + A3[3]);                                  \
      uint32_t h01 = cvtpk(v0, v1), h23 = cvtpk(v2, v3);                         \
      float p0 = v0 - bitf(h01 << 16);                                           \
      float p1 = v1 - bitf(h01 & 0xffff0000u);                                   \
      float p2 = v2 - bitf(h23 << 16);                                           \
      float p3 = v3 - bitf(h23 & 0xffff0000u);                                   \
      uint32_t l01 = cvtpk(p0, p1), l23 = cvtpk(p2, p3);                         \
      int2 wv; wv.x = (int)h01; wv.y = (int)h23;                                 \
      *(int2*)&Hhi[NXT][n][wbase + g8] = wv;                                     \
      wv.x = (int)l01; wv.y = (int)l23;                                          \
      *(int2*)&Hlo[NXT][n][wbase + g8] = wv;                                     \
    }                                                                            \
    {                                                                            \
      float v0 = clamp1(B1[0] + B2[0] + B3[0]);                                  \
      float v1 = clamp1(B1[1] + B2[1] + B3[1]);                                  \
      float v2 = clamp1(B1[2] + B2[2] + B3[2]);                                  \
      float v3 = clamp1(B1[3] + B2[3] + B3[3]);                                  \
      uint32_t h01 = cvtpk(v0, v1), h23 = cvtpk(v2, v3);                         \
      float p0 = v0 - bitf(h01 << 16);                                           \
      float p1 = v1 - bitf(h01 & 0xffff0000u);                                   \
      float p2 = v2 - bitf(h23 << 16);                                           \
      float p3 = v3 - bitf(h23 & 0xffff0000u);                                   \
      uint32_t l01 = cvtpk(p0, p1), l23 = cvtpk(p2, p3);                         \
      int2 wv; wv.x = (int)h01; wv.y = (int)h23;                                 \
      *(int2*)&Hhi[NXT][n][wbase + g8 + 4] = wv;                                 \
      wv.x = (int)l01; wv.y = (int)l23;                                          \
      *(int2*)&Hlo[NXT][n][wbase + g8 + 4] = wv;                                 \
    }                                                                            \
    __syncthreads();                                                             \
  } while (0)

__global__ __launch_bounds__(NTHR, 1) void rnn_mfma6_kernel(
    const float* __restrict__ xs,     // [B, T, D]
    const float* __restrict__ W_in,   // [H, D]
    const float* __restrict__ W_h,    // [H, H]
    const float* __restrict__ W_out,  // [O, H]
    float* __restrict__ out)          // [B, O]
{
    __shared__ __align__(16) short Hhi[2][NB][ROWS];
    __shared__ __align__(16) short Hlo[2][NB][ROWS];

    const int tid  = threadIdx.x;
    const int lane = tid & 63;
    const int wid  = tid >> 6;       // wave 0..3
    const int n    = lane & 15;      // batch col / A-row within tile
    const int g    = lane >> 4;      // k-group 0..3
    const int g8   = g * 8;
    const int wbase = 32 * wid;      // write base: pos = 32*wid + 8g + 4*mi
    const int b0   = blockIdx.x * NB;

    // clamped x element indices for this lane (d = 4g+j, clamped into [0,12])
    const int d0 = (4 * g + 0 > 12) ? 12 : 4 * g + 0;
    const int d1 = (4 * g + 1 > 12) ? 12 : 4 * g + 1;
    const int d2 = (4 * g + 2 > 12) ? 12 : 4 * g + 2;
    const int d3 = (4 * g + 3 > 12) ? 12 : 4 * g + 3;

    // ---- A fragments: rows 16*(2*wid+mi)+n, bf16 hi/lo, 5 k-tiles ----
    v8s whiA[5], wloA[5], whiB[5], wloB[5];
    #pragma unroll
    for (int mi = 0; mi < 2; ++mi) {
        const int row = 16 * (wid * 2 + mi) + n;
        #pragma unroll
        for (int kt = 0; kt < 5; ++kt) {
            v8s h8, l8;
            #pragma unroll
            for (int j = 0; j < 4; ++j) {
                float w1, w2;
                if (kt < 4) {
                    w1 = W_h[row * RNN_H + 32 * kt + 4 * g + j];
                    w2 = W_h[row * RNN_H + 32 * kt + 16 + 4 * g + j];
                } else {
                    const int kx = 4 * g + j;
                    w1 = (kx < RNN_D) ? W_in[row * RNN_D + kx] : 0.0f;
                    w2 = 0.0f;
                }
                const short h1 = f2bf(w1);
                const short h2 = f2bf(w2);
                h8[j] = h1; h8[4 + j] = h2;
                l8[j] = f2bf(w1 - bf2fs(h1));
                l8[4 + j] = f2bf(w2 - bf2fs(h2));
            }
            if (mi == 0) { whiA[kt] = h8; wloA[kt] = l8; }
            else         { whiB[kt] = h8; wloB[kt] = l8; }
        }
    }

    // ---- zero-init buffer 0 (h0 = 0) ----
    for (int idx = tid; idx < NB * ROWS; idx += NTHR) {
        (&Hhi[0][0][0])[idx] = 0;
        (&Hlo[0][0][0])[idx] = 0;
    }

    // ---- x prefetch depth 2, named scalars ----
    const float* xrow = xs + (size_t)(b0 + n) * RNN_T * RNN_D;
    float xa0 = xrow[d0], xa1 = xrow[d1], xa2 = xrow[d2], xa3 = xrow[d3];
    float xb0 = xrow[RNN_D + d0], xb1 = xrow[RNN_D + d1];
    float xb2 = xrow[RNN_D + d2], xb3 = xrow[RNN_D + d3];
    __syncthreads();

    // ---- recurrence, x2 unrolled (buf 0 -> 1 -> 0 ...) ----
    for (int t = 0; t < RNN_T; t += 2) {
        STEP(0, 1, xa0, xa1, xa2, xa3, t + 2);
        STEP(1, 0, xb0, xb1, xb2, xb3, t + 3);
    }

    // ---- epilogue: out[b][o] = sum_i W_out[o][i] * h_T[i]  (final h in buf 0) ----
    if (wid == 0 && lane < NB * RNN_O) {
        const int nn = lane & 15;
        const int o  = lane >> 4;
        float acc = 0.0f;
        for (int i = 0; i < RNN_H; ++i) {
            const int pos = 32 * (i >> 5) + 8 * ((i >> 2) & 3)
                          + 4 * ((i >> 4) & 1) + (i & 3);
            const float hv = bf2fs(Hhi[0][nn][pos]) + bf2fs(Hlo[0][nn][pos]);
            acc = fmaf(W_out[o * RNN_H + i], hv, acc);
        }
        out[(size_t)(b0 + nn) * RNN_O + o] = acc;
    }
}

extern "C" void kernel_launch(void* const* d_in, const int* in_sizes, int n_in,
                              void* d_out, int out_size, void* d_ws, size_t ws_size,
                              hipStream_t stream) {
    const float* xs    = (const float*)d_in[0];
    const float* W_in  = (const float*)d_in[1];
    const float* W_h   = (const float*)d_in[2];
    const float* W_out = (const float*)d_in[3];
    float* out = (float*)d_out;

    rnn_mfma6_kernel<<<RNN_B / NB, NTHR, 0, stream>>>(xs, W_in, W_h, W_out, out);
}